// Round 14
// baseline (1929.243 us; speedup 1.0000x reference)
//
#include <hip/hip_runtime.h>
#include <hip/hip_bf16.h>
#include <hip/hip_fp16.h>

// GRU B=64 S=2048 I=256 H=256, fp32 in/out.
// Phase 1 (R13): fused cvt+GEMM: XG[m][768] = (x@[Wz|Wr|Wh] + bias) * gs,
//   gs = -log2e (z,r) / -2log2e (h) -- prescaled exp2 args.
// Phase 2 (R14): i8 K=64 MFMA recurrence. R13 lesson: removing ALL vmcnt
//   waits saturated the vmem queue (4 ops/step/wave, cap ~63) -> every
//   memory op stalled at issue; overhead 560->1350cy while pipe stayed at
//   770cy (counters proved it). Fix = counted drain (T4): s_waitcnt
//   vmcnt(8) lgkmcnt(0) + raw s_barrier -- bounds in-flight to 2 steps,
//   stores drain lazily off-path, x-loads (2-step-ahead) still covered.

#define S_LEN 2048
#define BATCH 64
#define HDIM  256
#define NGATE 768
#define M_TOTAL (BATCH * S_LEN)  // 131072

typedef _Float16 h8_t __attribute__((ext_vector_type(8)));
typedef float    f32x4 __attribute__((ext_vector_type(4)));
typedef int      i32x4 __attribute__((ext_vector_type(4)));

static __device__ __forceinline__ float h2f(unsigned short s) {
    _Float16 h; __builtin_memcpy(&h, &s, 2); return (float)h;
}
static __device__ __forceinline__ unsigned short f2h(float f) {
    _Float16 h = (_Float16)f; unsigned short s; __builtin_memcpy(&s, &h, 2); return s;
}

// ---------------- prep kernels ----------------

__global__ void k_prep_w(const float* __restrict__ Wz, const float* __restrict__ Wr,
                         const float* __restrict__ Wh,
                         const float* __restrict__ bz, const float* __restrict__ br,
                         const float* __restrict__ bh,
                         const float* __restrict__ buz, const float* __restrict__ bur,
                         unsigned short* __restrict__ Wt, float* __restrict__ biascat) {
    int n = blockIdx.x;       // 0..767
    int k = threadIdx.x;      // 0..255
    int g = n >> 8, h = n & 255;
    const float* W = (g == 0) ? Wz : (g == 1) ? Wr : Wh;
    Wt[n * 256 + k] = f2h(W[k * 256 + h]);
    if (k == 0) {
        float bias = (g == 0) ? (bz[h] + buz[h]) : (g == 1) ? (br[h] + bur[h]) : bh[h];
        biascat[n] = bias;
    }
}

// int8 B-fragments for mfma_i32_16x16x64_i8 + per-column descale factors.
// Lane l supplies B[k][col]: col = nt*16 + (l&15), k = ks*64 + (l>>4)*16 + e.
// Ufrag[(((g*16+nt)*4+ks)*64 + l)*16 + e] = round(U_g[k][col] * s_col)
// invU[g*256+col] = maxk|U| / (127*127)
__global__ void k_prep_uq(const float* __restrict__ Uz, const float* __restrict__ Ur,
                          const float* __restrict__ Uh,
                          signed char* __restrict__ Ufrag, float* __restrict__ invU) {
    int blk = blockIdx.x;           // g*256 + col
    int g = blk >> 8, col = blk & 255;
    int k = threadIdx.x;            // 0..255
    const float* U = (g == 0) ? Uz : (g == 1) ? Ur : Uh;
    float v = U[k * 256 + col];
    __shared__ float red[256];
    red[k] = fabsf(v);
    __syncthreads();
    for (int off = 128; off > 0; off >>= 1) {
        if (k < off) red[k] = fmaxf(red[k], red[k + off]);
        __syncthreads();
    }
    float m = red[0];
    float s = (m > 0.0f) ? 127.0f / m : 0.0f;
    int q = __float2int_rn(v * s);
    q = max(-127, min(127, q));
    int ks = k >> 6, l4 = (k >> 4) & 3, e = k & 15;
    int l = l4 * 16 + (col & 15), nt = col >> 4;
    Ufrag[((size_t)(((g * 16 + nt) * 4 + ks) * 64 + l)) * 16 + e] = (signed char)q;
    if (k == 0) invU[g * 256 + col] = m * (1.0f / 16129.0f);
}

// ---------------- phase 1: fused cvt + input GEMM ----------------
// One WG per m-tile (128 rows). A staged once (fp32 -> fp16 inline);
// loop over 6 n-blocks of 128 cols. Epilogue scales by gate log2e factor.

#define LDT 264  // 256 + 8 halves per LDS row

__global__ __launch_bounds__(256) void k_gemm_x(const float* __restrict__ x,
                                                const unsigned short* __restrict__ Wt,
                                                const float* __restrict__ biascat,
                                                unsigned short* __restrict__ XG) {
    __shared__ unsigned short As[128 * LDT];
    __shared__ unsigned short Bs[128 * LDT];
    int tid = threadIdx.x;
    int m0 = blockIdx.x * 128;

    // stage A: 128 rows x 256 k, fp32 global -> fp16 LDS
    {
        const float4* x4 = (const float4*)x;
#pragma unroll
        for (int i = 0; i < 16; i++) {
            int chunk = tid + i * 256;       // 0..4095
            int row = chunk >> 5;
            int c8  = (chunk & 31) * 8;
            size_t fidx = (size_t)(m0 + row) * 64 + (c8 >> 2);
            float4 va = x4[fidx];
            float4 vb = x4[fidx + 1];
            ushort4 o1, o2;
            o1.x = f2h(va.x); o1.y = f2h(va.y); o1.z = f2h(va.z); o1.w = f2h(va.w);
            o2.x = f2h(vb.x); o2.y = f2h(vb.y); o2.z = f2h(vb.z); o2.w = f2h(vb.w);
            *(ushort4*)(As + row * LDT + c8) = o1;
            *(ushort4*)(As + row * LDT + c8 + 4) = o2;
        }
    }

    int lane = tid & 63, wv = tid >> 6;
    int mw = (wv & 1) * 64, nw = (wv >> 1) * 64;
    int lr = lane & 15, lg = lane >> 4;

    for (int nb = 0; nb < 6; nb++) {
        int n0 = nb * 128;
        float gs = (nb < 4) ? -1.44269504f : -2.88539008f;

        __syncthreads();   // A ready (nb=0) / prev compute done reading Bs
        {
            const unsigned short* gb = Wt + (size_t)n0 * 256;
#pragma unroll
            for (int i = 0; i < 16; i++) {
                int chunk = tid + i * 256;
                int row = chunk >> 5;
                int c8  = (chunk & 31) * 8;
                uint4 vb = *(const uint4*)(gb + row * 256 + c8);
                *(uint4*)(Bs + row * LDT + c8) = vb;
            }
        }
        __syncthreads();

        f32x4 acc[4][4] = {};
#pragma unroll
        for (int k = 0; k < 8; k++) {
            h8_t a[4], b[4];
#pragma unroll
            for (int i = 0; i < 4; i++)
                a[i] = *(const h8_t*)(As + (mw + i * 16 + lr) * LDT + k * 32 + lg * 8);
#pragma unroll
            for (int jj = 0; jj < 4; jj++)
                b[jj] = *(const h8_t*)(Bs + (nw + jj * 16 + lr) * LDT + k * 32 + lg * 8);
#pragma unroll
            for (int i = 0; i < 4; i++)
#pragma unroll
                for (int jj = 0; jj < 4; jj++)
                    acc[i][jj] = __builtin_amdgcn_mfma_f32_16x16x32_f16(a[i], b[jj], acc[i][jj], 0, 0, 0);
        }

#pragma unroll
        for (int jj = 0; jj < 4; jj++) {
            int gcol = n0 + nw + jj * 16 + lr;
            float bias = biascat[gcol];
#pragma unroll
            for (int i = 0; i < 4; i++) {
                int grow = m0 + mw + i * 16 + lg * 4;
#pragma unroll
                for (int r = 0; r < 4; r++) {
                    XG[(size_t)(grow + r) * NGATE + gcol] = f2h((acc[i][jj][r] + bias) * gs);
                }
            }
        }
    }
}

// ---------------- phase 2: recurrence (i8 MFMA, 8 waves) ----------------
// 64 WGs x 512 threads (8 waves, 2/SIMD). Wave w owns N-tiles 2w, 2w+1.
// Tail: lane's tile = 2w + (l4&1); lanes l4>=2 duplicate; l4<2 write.
// In-loop barrier = s_waitcnt vmcnt(8) lgkmcnt(0) + raw s_barrier.

__global__ __launch_bounds__(512) __attribute__((amdgpu_waves_per_eu(2, 2)))
void k_gru(const i32x4* __restrict__ Ufrag,
           const float* __restrict__ invU,
           const unsigned short* __restrict__ XG,
           const float* __restrict__ buh,
           float* __restrict__ out) {
    __shared__ __align__(16) signed char hb[2][256];
    int tid = threadIdx.x;
    int lane = tid & 63, w = tid >> 6;       // wave 0..7, tiles 2w,2w+1
    int l4 = lane >> 4, lc = lane & 15;
    int b = blockIdx.x;
    int sel = l4 & 1;
    int c = (2 * w + sel) * 16 + lc;          // tail column (2x redundant)
    bool writer = (l4 < 2);

    // preamble: 24 i8 B-fragments = U[:, wave's 32 cols], 3 gates
    i32x4 uf[3][2][4];
#pragma unroll
    for (int g = 0; g < 3; g++)
#pragma unroll
        for (int i = 0; i < 2; i++)
#pragma unroll
            for (int ks = 0; ks < 4; ks++)
                uf[g][i][ks] = Ufrag[(size_t)((g * 16 + (2 * w + i)) * 4 + ks) * 64 + lane];
#pragma unroll
    for (int g = 0; g < 3; g++)
#pragma unroll
        for (int i = 0; i < 2; i++)
#pragma unroll
            for (int ks = 0; ks < 4; ks++)
                asm volatile("" : "+v"(uf[g][i][ks]));

    // persistent zero quad for ks=0 C-operand
    i32x4 zc = {};
    asm volatile("" : "+v"(zc));

    // descale factors with -log2e / -2log2e folded (XG is prescaled too)
    float invz = -1.44269504f * invU[0 * 256 + c];
    float invr = -1.44269504f * invU[1 * 256 + c];
    float invh = -2.88539008f * invU[2 * 256 + c];
    float buh_c = -2.88539008f * buh[c];

    if (tid < 64) ((int*)hb[0])[tid] = 0;    // h(-1) = 0

    const unsigned short* xb = XG + (size_t)b * S_LEN * NGATE;
    float* ob = out + (size_t)b * S_LEN * HDIM;

    // x pipeline, 2 steps deep: cur = x(t), nxt = x(t+1); xq -> x(t+2)
    const unsigned short* xq = xb + c;
    unsigned short xcz = xq[0], xcr = xq[256], xch = xq[512]; xq += NGATE;
    unsigned short xnz = xq[0], xnr = xq[256], xnh = xq[512]; xq += NGATE;
    float hm = 0.0f;
    __syncthreads();

    for (int t = 0; t < S_LEN; ++t) {
        const signed char* hrow = hb[t & 1];
        signed char* hdst = hb[(t & 1) ^ 1];

        // h fragments: 4 x b128, all issued up front
        const i32x4* hq = (const i32x4*)hrow;
        i32x4 a0 = hq[l4];
        i32x4 a1 = hq[4 + l4];
        i32x4 a2 = hq[8 + l4];
        i32x4 a3 = hq[12 + l4];

        i32x4 acc[3][2];
        __builtin_amdgcn_s_setprio(1);
#pragma unroll
        for (int g = 0; g < 3; g++)
#pragma unroll
            for (int i = 0; i < 2; i++)
                acc[g][i] = __builtin_amdgcn_mfma_i32_16x16x64_i8(a0, uf[g][i][0], zc, 0, 0, 0);
#pragma unroll
        for (int g = 0; g < 3; g++)
#pragma unroll
            for (int i = 0; i < 2; i++)
                acc[g][i] = __builtin_amdgcn_mfma_i32_16x16x64_i8(a1, uf[g][i][1], acc[g][i], 0, 0, 0);
#pragma unroll
        for (int g = 0; g < 3; g++)
#pragma unroll
            for (int i = 0; i < 2; i++)
                acc[g][i] = __builtin_amdgcn_mfma_i32_16x16x64_i8(a2, uf[g][i][2], acc[g][i], 0, 0, 0);
#pragma unroll
        for (int g = 0; g < 3; g++)
#pragma unroll
            for (int i = 0; i < 2; i++)
                acc[g][i] = __builtin_amdgcn_mfma_i32_16x16x64_i8(a3, uf[g][i][3], acc[g][i], 0, 0, 0);
        __builtin_amdgcn_s_setprio(0);

        // tail: select lane's tile acc; exp2-arg algebra (prescaled)
        float vz = (float)(sel ? acc[0][1][0] : acc[0][0][0]) * invz;
        float vr = (float)(sel ? acc[1][1][0] : acc[1][0][0]) * invr;
        float vh = (float)(sel ? acc[2][1][0] : acc[2][0][0]) * invh;

        float ez = __builtin_amdgcn_exp2f(h2f(xcz) + vz);
        float z  = __builtin_amdgcn_rcpf(1.0f + ez);
        float er = __builtin_amdgcn_exp2f(h2f(xcr) + vr);
        float r  = __builtin_amdgcn_rcpf(1.0f + er);
        float eh = __builtin_amdgcn_exp2f(h2f(xch) + r * (vh + buh_c));
        float cd = 2.0f * __builtin_amdgcn_rcpf(1.0f + eh) - 1.0f;
        hm = hm + z * (cd - hm);

        if (writer) {
            ob[(size_t)t * HDIM + c] = hm;
            hdst[c] = (signed char)__float2int_rn(hm * 127.0f);
        }

        // rotate x pipeline; issue loads for t+2 (last 2 iters read junk
        // past XG into Wt scratch -- never consumed, in-bounds of ws)
        xcz = xnz; xcr = xnr; xch = xnh;
        xnz = xq[0]; xnr = xq[256]; xnh = xq[512];
        xq += NGATE;

        // counted drain (T4): bound in-flight vmem to ~2 steps (4 ops/step)
        // -- stores retire lazily off-path, queue never saturates; lgkm 0
        // for the LDS h-exchange.
        asm volatile("s_waitcnt vmcnt(8) lgkmcnt(0)" ::: "memory");
        __builtin_amdgcn_s_barrier();
    }
}

// ---------------- launch ----------------

extern "C" void kernel_launch(void* const* d_in, const int* in_sizes, int n_in,
                              void* d_out, int out_size, void* d_ws, size_t ws_size,
                              hipStream_t stream) {
    const float* x   = (const float*)d_in[0];
    const float* Wz  = (const float*)d_in[1];
    const float* bz  = (const float*)d_in[2];
    const float* Wr  = (const float*)d_in[3];
    const float* br  = (const float*)d_in[4];
    const float* Wh  = (const float*)d_in[5];
    const float* bh  = (const float*)d_in[6];
    const float* Uz  = (const float*)d_in[7];
    const float* buz = (const float*)d_in[8];
    const float* Ur  = (const float*)d_in[9];
    const float* bur = (const float*)d_in[10];
    const float* Uh  = (const float*)d_in[11];
    const float* buh = (const float*)d_in[12];

    char* ws = (char*)d_ws;
    // layout: (unused 64MiB) | XG 192MiB | Wt 384KiB | Ufrag 192KiB | biascat 3KiB | invU 3KiB
    unsigned short* XG = (unsigned short*)(ws + 67108864);
    unsigned short* Wt = (unsigned short*)(ws + 268435456);
    signed char*    Ufrag = (signed char*)(ws + 268828672);
    float*          biascat = (float*)(ws + 269221888);
    float*          invU = (float*)(ws + 269225984);

    k_prep_w<<<768, 256, 0, stream>>>(Wz, Wr, Wh, bz, br, bh, buz, bur, Wt, biascat);
    k_prep_uq<<<768, 256, 0, stream>>>(Uz, Ur, Uh, Ufrag, invU);

    k_gemm_x<<<M_TOTAL / 128, 256, 0, stream>>>(x, Wt, biascat, XG);

    k_gru<<<BATCH, 512, 0, stream>>>((const i32x4*)Ufrag, invU, XG, buh, (float*)d_out);
}

// Round 15
// 1254.748 us; speedup vs baseline: 1.5376x; 1.5376x over previous
//
#include <hip/hip_runtime.h>
#include <hip/hip_bf16.h>
#include <hip/hip_fp16.h>

// GRU B=64 S=2048 I=256 H=256, fp32 in/out.
// Phase 1 (kept from R13, validated): fused cvt+GEMM, XG = (x@W + bias)*gs,
//   gs = -log2e (z,r) / -2log2e (h) -> prescaled exp2 args. -42us vs split.
// Phase 2 (R15 = faithful R12 revert + prescale tail, no setprio):
//   R13/R14 A/B proved the 1806us regression was the restructured loop
//   (asm barrier + hoisted h-frags + 2-deep x rotate), NOT the vmcnt count
//   (R13==R14 bit-identical). FETCH 99MB < XG 192MB -> XG largely L3-hits,
//   so __syncthreads' vmcnt(0) drain was nearly free all along. Revert to
//   the R12 body that measured 1136us twice: in-loop A-frag ds_reads,
//   __syncthreads, 1-step x prefetch, zc zero-quad, 2x-redundant tail.
//   setprio dropped: lockstep waves = T5-null regime (m190: slightly neg).

#define S_LEN 2048
#define BATCH 64
#define HDIM  256
#define NGATE 768
#define M_TOTAL (BATCH * S_LEN)  // 131072

typedef _Float16 h8_t __attribute__((ext_vector_type(8)));
typedef float    f32x4 __attribute__((ext_vector_type(4)));
typedef int      i32x4 __attribute__((ext_vector_type(4)));

static __device__ __forceinline__ float h2f(unsigned short s) {
    _Float16 h; __builtin_memcpy(&h, &s, 2); return (float)h;
}
static __device__ __forceinline__ unsigned short f2h(float f) {
    _Float16 h = (_Float16)f; unsigned short s; __builtin_memcpy(&s, &h, 2); return s;
}

// ---------------- prep kernels ----------------

__global__ void k_prep_w(const float* __restrict__ Wz, const float* __restrict__ Wr,
                         const float* __restrict__ Wh,
                         const float* __restrict__ bz, const float* __restrict__ br,
                         const float* __restrict__ bh,
                         const float* __restrict__ buz, const float* __restrict__ bur,
                         unsigned short* __restrict__ Wt, float* __restrict__ biascat) {
    int n = blockIdx.x;       // 0..767
    int k = threadIdx.x;      // 0..255
    int g = n >> 8, h = n & 255;
    const float* W = (g == 0) ? Wz : (g == 1) ? Wr : Wh;
    Wt[n * 256 + k] = f2h(W[k * 256 + h]);
    if (k == 0) {
        float bias = (g == 0) ? (bz[h] + buz[h]) : (g == 1) ? (br[h] + bur[h]) : bh[h];
        biascat[n] = bias;
    }
}

// int8 B-fragments for mfma_i32_16x16x64_i8 + per-column descale factors.
// Lane l supplies B[k][col]: col = nt*16 + (l&15), k = ks*64 + (l>>4)*16 + e.
// Ufrag[(((g*16+nt)*4+ks)*64 + l)*16 + e] = round(U_g[k][col] * s_col)
// invU[g*256+col] = maxk|U| / (127*127)
__global__ void k_prep_uq(const float* __restrict__ Uz, const float* __restrict__ Ur,
                          const float* __restrict__ Uh,
                          signed char* __restrict__ Ufrag, float* __restrict__ invU) {
    int blk = blockIdx.x;           // g*256 + col
    int g = blk >> 8, col = blk & 255;
    int k = threadIdx.x;            // 0..255
    const float* U = (g == 0) ? Uz : (g == 1) ? Ur : Uh;
    float v = U[k * 256 + col];
    __shared__ float red[256];
    red[k] = fabsf(v);
    __syncthreads();
    for (int off = 128; off > 0; off >>= 1) {
        if (k < off) red[k] = fmaxf(red[k], red[k + off]);
        __syncthreads();
    }
    float m = red[0];
    float s = (m > 0.0f) ? 127.0f / m : 0.0f;
    int q = __float2int_rn(v * s);
    q = max(-127, min(127, q));
    int ks = k >> 6, l4 = (k >> 4) & 3, e = k & 15;
    int l = l4 * 16 + (col & 15), nt = col >> 4;
    Ufrag[((size_t)(((g * 16 + nt) * 4 + ks) * 64 + l)) * 16 + e] = (signed char)q;
    if (k == 0) invU[g * 256 + col] = m * (1.0f / 16129.0f);
}

// ---------------- phase 1: fused cvt + input GEMM ----------------
// One WG per m-tile (128 rows). A staged once (fp32 -> fp16 inline);
// loop over 6 n-blocks of 128 cols. Epilogue scales by gate log2e factor.

#define LDT 264  // 256 + 8 halves per LDS row

__global__ __launch_bounds__(256) void k_gemm_x(const float* __restrict__ x,
                                                const unsigned short* __restrict__ Wt,
                                                const float* __restrict__ biascat,
                                                unsigned short* __restrict__ XG) {
    __shared__ unsigned short As[128 * LDT];
    __shared__ unsigned short Bs[128 * LDT];
    int tid = threadIdx.x;
    int m0 = blockIdx.x * 128;

    // stage A: 128 rows x 256 k, fp32 global -> fp16 LDS
    {
        const float4* x4 = (const float4*)x;
#pragma unroll
        for (int i = 0; i < 16; i++) {
            int chunk = tid + i * 256;       // 0..4095
            int row = chunk >> 5;
            int c8  = (chunk & 31) * 8;
            size_t fidx = (size_t)(m0 + row) * 64 + (c8 >> 2);
            float4 va = x4[fidx];
            float4 vb = x4[fidx + 1];
            ushort4 o1, o2;
            o1.x = f2h(va.x); o1.y = f2h(va.y); o1.z = f2h(va.z); o1.w = f2h(va.w);
            o2.x = f2h(vb.x); o2.y = f2h(vb.y); o2.z = f2h(vb.z); o2.w = f2h(vb.w);
            *(ushort4*)(As + row * LDT + c8) = o1;
            *(ushort4*)(As + row * LDT + c8 + 4) = o2;
        }
    }

    int lane = tid & 63, wv = tid >> 6;
    int mw = (wv & 1) * 64, nw = (wv >> 1) * 64;
    int lr = lane & 15, lg = lane >> 4;

    for (int nb = 0; nb < 6; nb++) {
        int n0 = nb * 128;
        float gs = (nb < 4) ? -1.44269504f : -2.88539008f;

        __syncthreads();   // A ready (nb=0) / prev compute done reading Bs
        {
            const unsigned short* gb = Wt + (size_t)n0 * 256;
#pragma unroll
            for (int i = 0; i < 16; i++) {
                int chunk = tid + i * 256;
                int row = chunk >> 5;
                int c8  = (chunk & 31) * 8;
                uint4 vb = *(const uint4*)(gb + row * 256 + c8);
                *(uint4*)(Bs + row * LDT + c8) = vb;
            }
        }
        __syncthreads();

        f32x4 acc[4][4] = {};
#pragma unroll
        for (int k = 0; k < 8; k++) {
            h8_t a[4], b[4];
#pragma unroll
            for (int i = 0; i < 4; i++)
                a[i] = *(const h8_t*)(As + (mw + i * 16 + lr) * LDT + k * 32 + lg * 8);
#pragma unroll
            for (int jj = 0; jj < 4; jj++)
                b[jj] = *(const h8_t*)(Bs + (nw + jj * 16 + lr) * LDT + k * 32 + lg * 8);
#pragma unroll
            for (int i = 0; i < 4; i++)
#pragma unroll
                for (int jj = 0; jj < 4; jj++)
                    acc[i][jj] = __builtin_amdgcn_mfma_f32_16x16x32_f16(a[i], b[jj], acc[i][jj], 0, 0, 0);
        }

#pragma unroll
        for (int jj = 0; jj < 4; jj++) {
            int gcol = n0 + nw + jj * 16 + lr;
            float bias = biascat[gcol];
#pragma unroll
            for (int i = 0; i < 4; i++) {
                int grow = m0 + mw + i * 16 + lg * 4;
#pragma unroll
                for (int r = 0; r < 4; r++) {
                    XG[(size_t)(grow + r) * NGATE + gcol] = f2h((acc[i][jj][r] + bias) * gs);
                }
            }
        }
    }
}

// ---------------- phase 2: recurrence (i8 MFMA, 8 waves, R12 body) -----
// 64 WGs x 512 threads (8 waves, 2/SIMD). Wave w owns N-tiles 2w, 2w+1.
// Tail: lane's tile = 2w + (l4&1); lanes l4>=2 duplicate; l4<2 write.

__global__ __launch_bounds__(512) __attribute__((amdgpu_waves_per_eu(2, 2)))
void k_gru(const i32x4* __restrict__ Ufrag,
           const float* __restrict__ invU,
           const unsigned short* __restrict__ XG,
           const float* __restrict__ buh,
           float* __restrict__ out) {
    __shared__ __align__(16) signed char hb[2][256];
    int tid = threadIdx.x;
    int lane = tid & 63, w = tid >> 6;       // wave 0..7, tiles 2w,2w+1
    int l4 = lane >> 4, lc = lane & 15;
    int b = blockIdx.x;
    int sel = l4 & 1;
    int c = (2 * w + sel) * 16 + lc;          // tail column (2x redundant)
    bool writer = (l4 < 2);

    // preamble: 24 i8 B-fragments = U[:, wave's 32 cols], 3 gates
    i32x4 uf[3][2][4];
#pragma unroll
    for (int g = 0; g < 3; g++)
#pragma unroll
        for (int i = 0; i < 2; i++)
#pragma unroll
            for (int ks = 0; ks < 4; ks++)
                uf[g][i][ks] = Ufrag[(size_t)((g * 16 + (2 * w + i)) * 4 + ks) * 64 + lane];
    // pin: asm-touched values cannot be rematerialized into the loop
#pragma unroll
    for (int g = 0; g < 3; g++)
#pragma unroll
        for (int i = 0; i < 2; i++)
#pragma unroll
            for (int ks = 0; ks < 4; ks++)
                asm volatile("" : "+v"(uf[g][i][ks]));

    // persistent zero quad for ks=0 C-operand (no per-step acc zero-init)
    i32x4 zc = {};
    asm volatile("" : "+v"(zc));

    // descale factors with -log2e / -2log2e folded (XG is prescaled too)
    float invz = -1.44269504f * invU[0 * 256 + c];
    float invr = -1.44269504f * invU[1 * 256 + c];
    float invh = -2.88539008f * invU[2 * 256 + c];
    float buh_c = -2.88539008f * buh[c];

    if (tid < 64) ((int*)hb[0])[tid] = 0;    // h(-1) = 0

    const unsigned short* xb = XG + (size_t)b * S_LEN * NGATE;
    float* ob = out + (size_t)b * S_LEN * HDIM;

    const unsigned short* xp = xb + c;        // advancing gate-input pointer
    unsigned short pz = xp[0], pr = xp[256], ph = xp[512];  // x(0)
    xp += NGATE;
    float hm = 0.0f;                          // fp32 master h for col c
    __syncthreads();

    for (int t = 0; t < S_LEN; ++t) {
        const signed char* hrow = hb[t & 1];
        signed char* hdst = hb[(t & 1) ^ 1];

        i32x4 acc[3][2];
        {   // ks = 0: C = persistent zero quad
            i32x4 a = *(const i32x4*)(hrow + l4 * 16);
#pragma unroll
            for (int g = 0; g < 3; g++)
#pragma unroll
                for (int i = 0; i < 2; i++)
                    acc[g][i] = __builtin_amdgcn_mfma_i32_16x16x64_i8(a, uf[g][i][0], zc, 0, 0, 0);
        }
#pragma unroll
        for (int ks = 1; ks < 4; ks++) {
            // A-frag: h_q[k], k = ks*64 + l4*16 + e; 16B broadcast per lane
            // group, 4 distinct addrs, conflict-free. All A rows identical
            // -> D rows identical -> acc[..][0] valid in every lane.
            i32x4 a = *(const i32x4*)(hrow + ks * 64 + l4 * 16);
#pragma unroll
            for (int g = 0; g < 3; g++)
#pragma unroll
                for (int i = 0; i < 2; i++)
                    acc[g][i] = __builtin_amdgcn_mfma_i32_16x16x64_i8(a, uf[g][i][ks], acc[g][i], 0, 0, 0);
        }

        // tail: select lane's tile acc (1 cndmask/gate); prescaled exp2 algebra
        float vz = (float)(sel ? acc[0][1][0] : acc[0][0][0]) * invz;
        float vr = (float)(sel ? acc[1][1][0] : acc[1][0][0]) * invr;
        float vh = (float)(sel ? acc[2][1][0] : acc[2][0][0]) * invh;

        float ez = __builtin_amdgcn_exp2f(h2f(pz) + vz);
        float z  = __builtin_amdgcn_rcpf(1.0f + ez);
        float er = __builtin_amdgcn_exp2f(h2f(pr) + vr);
        float r  = __builtin_amdgcn_rcpf(1.0f + er);
        float eh = __builtin_amdgcn_exp2f(h2f(ph) + r * (vh + buh_c));
        float cd = 2.0f * __builtin_amdgcn_rcpf(1.0f + eh) - 1.0f;
        hm = hm + z * (cd - hm);

        if (writer) {
            ob[(size_t)t * HDIM + c] = hm;
            hdst[c] = (signed char)__float2int_rn(hm * 127.0f);
        }

        pz = xp[0]; pr = xp[256]; ph = xp[512];   // prefetch x(t+1)
        xp += NGATE;                               // (tail reads past XG land
                                                   //  in Wt scratch; unused)
        __syncthreads();
    }
}

// ---------------- launch ----------------

extern "C" void kernel_launch(void* const* d_in, const int* in_sizes, int n_in,
                              void* d_out, int out_size, void* d_ws, size_t ws_size,
                              hipStream_t stream) {
    const float* x   = (const float*)d_in[0];
    const float* Wz  = (const float*)d_in[1];
    const float* bz  = (const float*)d_in[2];
    const float* Wr  = (const float*)d_in[3];
    const float* br  = (const float*)d_in[4];
    const float* Wh  = (const float*)d_in[5];
    const float* bh  = (const float*)d_in[6];
    const float* Uz  = (const float*)d_in[7];
    const float* buz = (const float*)d_in[8];
    const float* Ur  = (const float*)d_in[9];
    const float* bur = (const float*)d_in[10];
    const float* Uh  = (const float*)d_in[11];
    const float* buh = (const float*)d_in[12];

    char* ws = (char*)d_ws;
    // layout: (unused 64MiB) | XG 192MiB | Wt 384KiB | Ufrag 192KiB | biascat 3KiB | invU 3KiB
    unsigned short* XG = (unsigned short*)(ws + 67108864);
    unsigned short* Wt = (unsigned short*)(ws + 268435456);
    signed char*    Ufrag = (signed char*)(ws + 268828672);
    float*          biascat = (float*)(ws + 269221888);
    float*          invU = (float*)(ws + 269225984);

    k_prep_w<<<768, 256, 0, stream>>>(Wz, Wr, Wh, bz, br, bh, buz, bur, Wt, biascat);
    k_prep_uq<<<768, 256, 0, stream>>>(Uz, Ur, Uh, Ufrag, invU);

    k_gemm_x<<<M_TOTAL / 128, 256, 0, stream>>>(x, Wt, biascat, XG);

    k_gru<<<BATCH, 512, 0, stream>>>((const i32x4*)Ufrag, invU, XG, buh, (float*)d_out);
}